// Round 12
// baseline (318.070 us; speedup 1.0000x reference)
//
#include <hip/hip_runtime.h>

// Problem constants: H=8, B=16, G=512, NQ=512, D=512, KD=VD=64, E=512, NORM=0.125
using u8 = unsigned char;
using u16 = unsigned short;
using u32 = unsigned int;
using u64 = unsigned long long;

typedef __attribute__((ext_vector_type(8))) __bf16 bf16x8;
typedef __attribute__((ext_vector_type(2))) __bf16 bf16x2;
typedef __attribute__((ext_vector_type(8))) u16 u16x8;
typedef __attribute__((ext_vector_type(4))) float f32x4;
typedef __attribute__((ext_vector_type(2))) float f32x2;
typedef __attribute__((ext_vector_type(2))) u32 u32x2;

#define MFMA16(A, B, C) __builtin_amdgcn_mfma_f32_16x16x32_bf16((A), (B), (C), 0, 0, 0)

#if __has_builtin(__builtin_amdgcn_exp2f)
#define EXP2(x) __builtin_amdgcn_exp2f(x)
#else
#define EXP2(x) __expf((x)*0.69314718055994531f)
#endif

__device__ __forceinline__ u16 f2bf(float f) {
  u32 u = __builtin_bit_cast(u32, f);
  u += 0x7fffu + ((u >> 16) & 1u);   // round-to-nearest-even
  return (u16)(u >> 16);
}

// async 16B/lane global->LDS DMA. lds dest must be wave-uniform base; lane i
// lands at base + i*16.
__device__ __forceinline__ void gl_lds16(const void* g, void* l) {
  __builtin_amdgcn_global_load_lds(
      (const __attribute__((address_space(1))) void*)g,
      (__attribute__((address_space(3))) void*)l, 16, 0, 0);
}

// ---------------------------------------------------------------- prep
//   prep_main_k: [0,512) pack_rows | [512,896) prep_w | [896,960) prep_wout
//                | [960,3008) prep_q
// (round-10 structure: wide prep_w, bit-transpose pack_cols — 104us -> fixed)

struct PrepArgs {
  const float* q; const int* att; const int* grp; const int* sd;
  const float* w[12]; const float* wout;
  u16* qb; u16* Wbt; u16* Wot; u64* RB;
};

__global__ __launch_bounds__(256) void prep_main_k(PrepArgs a) {
  int bid = blockIdx.x;
  int t = threadIdx.x;
  if (bid < 512) {
    // ---- pack_rows: RB c0/c2/c3 bits (coalesced over g) ----
    int wave = t >> 6, lane = t & 63;
    int b = bid >> 5, qc = bid & 31;
    int q0 = qc * 16 + wave * 4;
#pragma unroll
    for (int r = 0; r < 4; r++) {
      int q = q0 + r;
      size_t rbase = ((size_t)(b * 512 + q)) * 512;
#pragma unroll
      for (int gc = 0; gc < 8; gc++) {
        u64 m0 = __ballot(a.sd [rbase + gc * 64 + lane] != 0);
        u64 m2 = __ballot(a.att[rbase + gc * 64 + lane] != 0);
        u64 m3 = __ballot(a.grp[rbase + gc * 64 + lane] != 0);
        if (lane == 0) {
          size_t ob = ((size_t)(b * 4) * 512 + q) * 8 + gc;
          a.RB[ob]            = m0;   // c0
          a.RB[ob + 2 * 4096] = m2;   // c2
          a.RB[ob + 3 * 4096] = m3;   // c3
        }
      }
    }
  } else if (bid < 896) {
    // ---- prep_w: Wbt[(iw*512+h*64+kk)][d] = W_iw[h][d][kk] * scale ----
    int nb = bid - 512;
    int iw = nb >> 5;
    int rest = nb & 31;
    int h = rest >> 2;
    int d0 = (rest & 3) * 128;
    int kk = t & 63;
    int db0 = t >> 6;
    float scale = ((iw % 3) == 0) ? 0.18033688011112042f : 1.0f;  // 0.125*log2e
    const float* W = a.w[iw] + ((size_t)(h * 512)) * 64 + kk;
    u16* dst = a.Wbt + ((size_t)(iw * 512 + h * 64 + kk)) * 512;
#pragma unroll
    for (int it = 0; it < 4; it++) {
      int d = d0 + (db0 + it * 4) * 8;
      float v0 = W[(size_t)(d + 0) * 64] * scale;
      float v1 = W[(size_t)(d + 1) * 64] * scale;
      float v2 = W[(size_t)(d + 2) * 64] * scale;
      float v3 = W[(size_t)(d + 3) * 64] * scale;
      float v4 = W[(size_t)(d + 4) * 64] * scale;
      float v5 = W[(size_t)(d + 5) * 64] * scale;
      float v6 = W[(size_t)(d + 6) * 64] * scale;
      float v7 = W[(size_t)(d + 7) * 64] * scale;
      u32 w0 = f2bf(v0) | ((u32)f2bf(v1) << 16);
      u32 w1 = f2bf(v2) | ((u32)f2bf(v3) << 16);
      u32 w2 = f2bf(v4) | ((u32)f2bf(v5) << 16);
      u32 w3 = f2bf(v6) | ((u32)f2bf(v7) << 16);
      *(uint4*)(dst + d) = make_uint4(w0, w1, w2, w3);
    }
  } else if (bid < 960) {
    // ---- Wot[h][e][v] = wout[h][v][e]; 64 blocks = (h, e-block of 64) ----
    int nb = bid - 896;
    int h = nb >> 3, e0 = (nb & 7) * 64;
    int ep = t >> 2;        // e' 0..63
    int vc = t & 3;         // v base = vc*16
    const float* src = a.wout + ((size_t)(h * 64)) * 512 + e0 + ep;
#pragma unroll
    for (int j = 0; j < 2; j++) {
      int v0 = vc * 16 + j * 8;
      u32 w0 = f2bf(src[(size_t)(v0 + 0) * 512]) | ((u32)f2bf(src[(size_t)(v0 + 1) * 512]) << 16);
      u32 w1 = f2bf(src[(size_t)(v0 + 2) * 512]) | ((u32)f2bf(src[(size_t)(v0 + 3) * 512]) << 16);
      u32 w2 = f2bf(src[(size_t)(v0 + 4) * 512]) | ((u32)f2bf(src[(size_t)(v0 + 5) * 512]) << 16);
      u32 w3 = f2bf(src[(size_t)(v0 + 6) * 512]) | ((u32)f2bf(src[(size_t)(v0 + 7) * 512]) << 16);
      *(uint4*)&a.Wot[((size_t)(h * 512 + e0 + ep)) * 64 + v0] = make_uint4(w0, w1, w2, w3);
    }
  } else {
    // ---- prep_q: f32 -> bf16, vectorized ----
    int idx = (bid - 960) * 256 + t;
    const float4* p = (const float4*)a.q + (size_t)idx * 2;
    float4 x = p[0], y = p[1];
    u32 w0 = f2bf(x.x) | ((u32)f2bf(x.y) << 16);
    u32 w1 = f2bf(x.z) | ((u32)f2bf(x.w) << 16);
    u32 w2 = f2bf(y.x) | ((u32)f2bf(y.y) << 16);
    u32 w3 = f2bf(y.z) | ((u32)f2bf(y.w) << 16);
    ((uint4*)a.qb)[idx] = make_uint4(w0, w1, w2, w3);
  }
}

// c1 = (q,g)-bit-transpose of c2, per b. One wave per 64x64-bit tile.
__global__ __launch_bounds__(256) void pack_cols_t_k(u64* __restrict__ RB) {
  int t = threadIdx.x;
  int wave = t >> 6, lane = t & 63;
  int tile = blockIdx.x * 4 + wave;           // 0..1023
  int b = tile >> 6, qc = (tile >> 3) & 7, gc = tile & 7;
  u64 R = RB[((size_t)(b * 4 + 2) * 512 + gc * 64 + lane) * 8 + qc];
  u64 out = 0;
#pragma unroll
  for (int j = 0; j < 64; j++) {
    u64 bal = __ballot(((R >> j) & 1) != 0);
    if (lane == j) out = bal;
  }
  RB[((size_t)(b * 4 + 1) * 512 + qc * 64 + lane) * 8 + gc] = out;
}

// ---------------------------------------------------------------- pass A: all 12 projections
// C(8192 x 6144) = qb(8192 x 512) * W(512 x 6144). 128x128 tile, BK=64, 4 waves.
// Round-5 main loop (reg-staged prefetch; loads pinned early by the GST
// consumer — rounds 6/7 proved MFMA-fed loads get sunk). NEW (round 12):
// epilogue runs in TWO HALVES with a [64][136] Cs tile, capping kernel LDS
// at EXACTLY 32768B -> 5 blocks/CU (was 34816 -> 4). Cross-block TLP is the
// only mechanism hiding this kernel's barrier drains (rounds 2/6/7), so
// +25% resident blocks should convert directly to less stall.
__global__ __launch_bounds__(256) void gemm_proj_k(const u16* __restrict__ qb,
                                                   const u16* __restrict__ Wbt,
                                                   u16* __restrict__ P) {
  __shared__ __align__(16) u16 smem[16384];  // As 8192 | Bs 8192 (32KB exactly); Cs 64x136 overlays
  u16* As = smem;
  u16* Bs = smem + 8192;
  int t = threadIdx.x;
  int wave = t >> 6, lane = t & 63, quad = lane >> 4, l16 = lane & 15;
  int m0w = (wave >> 1) * 64, n0w = (wave & 1) * 64;
  int bm = blockIdx.x, bn = blockIdx.y;
  f32x4 acc[4][4] = {};
  int lr8 = lane >> 3;                 // 0..7
  int lc8 = (lane & 7) ^ lr8;         // swizzled logical chunk to fetch
  const u16* ag = qb  + ((size_t)(bm * 128 + wave * 32 + lr8)) * 512 + lc8 * 8;
  const u16* bg = Wbt + ((size_t)(bn * 128 + wave * 32 + lr8)) * 512 + lc8 * 8;
  char* AsB = (char*)As;
  char* BsB = (char*)Bs;
  int stO = wave * 4096 + lane * 16;   // byte offset of this thread's 16B slot (j=0)

  uint4 sA0, sA1, sA2, sA3, sB0, sB1, sB2, sB3;
// named-scalar staging; macros = textual inline, nothing address-taken (rule #20)
#define GLD(k0_) {                                          \
    sA0 = *(const uint4*)(ag + 0 * 4096 + (k0_));           \
    sA1 = *(const uint4*)(ag + 1 * 4096 + (k0_));           \
    sA2 = *(const uint4*)(ag + 2 * 4096 + (k0_));           \
    sA3 = *(const uint4*)(ag + 3 * 4096 + (k0_));           \
    sB0 = *(const uint4*)(bg + 0 * 4096 + (k0_));           \
    sB1 = *(const uint4*)(bg + 1 * 4096 + (k0_));           \
    sB2 = *(const uint4*)(bg + 2 * 4096 + (k0_));           \
    sB3 = *(const uint4*)(bg + 3 * 4096 + (k0_)); }
#define GST() {                                             \
    *(uint4*)(AsB + stO)        = sA0;                      \
    *(uint4*)(AsB + stO + 1024) = sA1;                      \
    *(uint4*)(AsB + stO + 2048) = sA2;                      \
    *(uint4*)(AsB + stO + 3072) = sA3;                      \
    *(uint4*)(BsB + stO)        = sB0;                      \
    *(uint4*)(BsB + stO + 1024) = sB1;                      \
    *(uint4*)(BsB + stO + 2048) = sB2;                      \
    *(uint4*)(BsB + stO + 3072) = sB3; }

  // prologue: stage K-step 0
  GLD(0);
  GST();
  __syncthreads();

  for (int ks = 0; ks < 8; ks++) {
    int k0 = ks * 64;
    if (ks < 7) GLD(k0 + 64);          // flies under the compute below
#pragma unroll
    for (int kc = 0; kc < 2; kc++) {
      bf16x8 am[4], bnf[4];
#pragma unroll
      for (int i = 0; i < 4; i++) {
        int ca = ((kc * 4 + quad) ^ (l16 & 7)) * 8;
        am[i]  = *(const bf16x8*)&As[(m0w + i * 16 + l16) * 64 + ca];
        bnf[i] = *(const bf16x8*)&Bs[(n0w + i * 16 + l16) * 64 + ca];
      }
#pragma unroll
      for (int mt = 0; mt < 4; mt++)
#pragma unroll
        for (int nt = 0; nt < 4; nt++)
          acc[mt][nt] = MFMA16(am[mt], bnf[nt], acc[mt][nt]);
    }
    if (ks < 7) {
      __syncthreads();                 // all LDS reads of step ks done
      GST();                           // own loads ~landed (issued ~770cy ago)
      __syncthreads();                 // stores visible
    }
  }
  // -------- epilogue: two-half LDS-staged coalesced stores (32KB cap) -----
  int iw = bn >> 2;                  // both 64-col groups share iw
  bool isV = (iw % 3) == 2;
  int b  = bm >> 2;
  int n0 = (bm & 3) * 128;
  u16 (*Cs)[136] = (u16(*)[136])smem;  // 64 x 136 u16 = 17,408 B
  // half membership: !isV rows come from m0w (waves {0,1}|{2,3});
  //                   isV rows come from n0w (waves {0,2}|{1,3}).
  int wsel = isV ? (wave & 1) : (wave >> 1);
#pragma unroll
  for (int half = 0; half < 2; half++) {
    __syncthreads();                 // main-loop reads / prior half's stores done
    if (wsel == half) {
#pragma unroll
      for (int mt = 0; mt < 4; mt++)
#pragma unroll
        for (int nt = 0; nt < 4; nt++)
#pragma unroll
          for (int r = 0; r < 4; r++) {
            int rm = m0w + mt * 16 + quad * 4 + r;
            int cn = n0w + nt * 16 + l16;
            u16 v = f2bf(acc[mt][nt][r]);
            if (!isV) Cs[rm & 63][cn] = v;
            else      Cs[cn & 63][rm] = v;
          }
    }
    __syncthreads();
#pragma unroll
    for (int p = 0; p < 4; p++) {
      int idx = p * 256 + t;
      int seg  = idx & 15;
      int sub  = idx >> 4;           // 0..63
      int crow = half * 64 + sub;
      uint4 v = *(const uint4*)&Cs[sub][seg * 8];
      if (!isV) {
        int col = seg * 8;
        int cg = col >> 6, k = col & 63;
        int h = (bn * 2 + cg) & 7;
        u16* dst = P + ((size_t)((iw * 8 + h) * 16 + b)) * 32768 + (size_t)(n0 + crow) * 64 + k;
        *(uint4*)dst = v;
      } else {
        int cg = crow >> 6, k = crow & 63;
        int h = (bn * 2 + cg) & 7;
        u16* dst = P + ((size_t)((iw * 8 + h) * 16 + b)) * 32768 + (size_t)k * 512 + n0 + seg * 8;
        *(uint4*)dst = v;
      }
    }
  }
}

// ---------------------------------------------------------------- pass B: fused masked attention
// 1-D grid, 1024 blocks; block 256 = 4 waves, each wave owns 16 q-rows.
// XCD swizzle keeps each (b,h)'s 512KB K/V panel on one XCD's L2.
// T14 reg-staging with NAMED SCALARS ONLY (rule #20). Swapped QK^T
// (mfma(K,Q)); masked-exp packs via cvt_pk into b64 writes; ones-MFMA
// denominator; raw v_exp_f32 (weights pre-scaled by 0.125*log2e).
__global__ __launch_bounds__(256) void attn_k(const u16* __restrict__ P,
                                              const u64* __restrict__ RB,
                                              u16* __restrict__ heads) {
  __shared__ __align__(16) u16 QPs[4096];    // [64][64]: Q at class start, then P scratch
  __shared__ __align__(16) u16 Ks[4096];     // [64][64] chunk-swizzled
  __shared__ __align__(16) u16 Vs[4096];     // [v][g] chunk-swizzled
  __shared__ __align__(16) u64 Ms[64][10];   // row bitmasks, padded (conflict-free b64)
  int t = threadIdx.x;
  int wave = t >> 6, lane = t & 63, quad = lane >> 4, l16 = lane & 15;
  // id = 8*((bh>>3)*8 + qt) + (bh&7)  — bijective; id%8 keyed to bh
  int id = blockIdx.x;
  int r8 = id & 7, kk2 = id >> 3;
  int bh = ((kk2 >> 3) << 3) | r8;
  int qt = kk2 & 7;
  int b = bh & 15, h = bh >> 4;
  int q0 = qt * 64;
  int lr8 = lane >> 3, lc8 = (lane & 7) ^ lr8;
  f32x4 O0 = {}, O1 = {}, O2 = {}, O3 = {};
  f32x4 Oden = {};
  u16x8 ov = {0x3F80, 0x3F80, 0x3F80, 0x3F80, 0x3F80, 0x3F80, 0x3F80, 0x3F80};
  bf16x8 ones = __builtin_bit_cast(bf16x8, ov);   // bf16 1.0 x8

  uint4 rK0, rK1, rV0, rV1, rQ0, rQ1, rM;
  char* KsB = (char*)Ks;
  char* VsB = (char*)Vs;
  char* QsB = (char*)QPs;
  int stOff = (wave * 16 + lr8) * 128 + (lane & 7) * 16;   // +1024 for second 8 rows

// all staging through named scalars; macros = textual inline, nothing address-taken
#define LOADKV(c, g0) {                                                              \
    const u16* PK_ = P + ((size_t)((3 * (c) + 1) * 8 + h) * 16 + b) * 32768;         \
    const u16* PV_ = P + ((size_t)((3 * (c) + 2) * 8 + h) * 16 + b) * 32768;         \
    rK0 = *(const uint4*)(PK_ + (size_t)((g0) + wave * 16 + lr8) * 64 + lc8 * 8);    \
    rK1 = *(const uint4*)(PK_ + (size_t)((g0) + wave * 16 + 8 + lr8) * 64 + lc8 * 8);\
    rV0 = *(const uint4*)(PV_ + (size_t)(wave * 16 + lr8) * 512 + (g0) + lc8 * 8);   \
    rV1 = *(const uint4*)(PV_ + (size_t)(wave * 16 + 8 + lr8) * 512 + (g0) + lc8 * 8);}
#define STOREKV() {                                                                  \
    *(uint4*)(KsB + stOff)        = rK0;                                             \
    *(uint4*)(KsB + stOff + 1024) = rK1;                                             \
    *(uint4*)(VsB + stOff)        = rV0;                                             \
    *(uint4*)(VsB + stOff + 1024) = rV1; }
#define LOADQM(c) {                                                                  \
    const u16* PQ_ = P + ((size_t)((3 * (c)) * 8 + h) * 16 + b) * 32768;             \
    rQ0 = *(const uint4*)(PQ_ + (size_t)(q0 + wave * 16 + lr8) * 64 + lc8 * 8);      \
    rQ1 = *(const uint4*)(PQ_ + (size_t)(q0 + wave * 16 + 8 + lr8) * 64 + lc8 * 8);  \
    rM  = *(const uint4*)(RB + ((size_t)((b * 4 + (c)) * 512 + q0 + (t >> 2))) * 8 + (t & 3) * 2); }
#define STOREQM() {                                                                  \
    *(uint4*)(QsB + stOff)        = rQ0;                                             \
    *(uint4*)(QsB + stOff + 1024) = rQ1;                                             \
    *(uint4*)((char*)Ms + (t >> 2) * 80 + (t & 3) * 16) = rM; }

  // prologue: tile (c=0, gt=0)
  LOADKV(0, 0);
  LOADQM(0);
  STOREKV();
  STOREQM();
  __syncthreads();

  bf16x8 aq0, aq1;
  for (int tt = 0; tt < 32; tt++) {
    int gt = tt & 7;
    if (gt == 0) {                 // Q fragments gt-invariant: hoist (QPs then free for P)
      aq0 = *(const bf16x8*)&QPs[(wave * 16 + l16) * 64 + ((quad) ^ (l16 & 7)) * 8];
      aq1 = *(const bf16x8*)&QPs[(wave * 16 + l16) * 64 + ((4 + quad) ^ (l16 & 7)) * 8];
    }
    int nxt = tt + 1;
    int nc = nxt >> 3, ngt = nxt & 7;
    if (nxt < 32) {
      LOADKV(nc, ngt * 64);        // issue now; lands during compute below
      if (ngt == 0) LOADQM(nc);
    }
    // --- QK^T, swapped operands: D rows = g (A=K), cols = q (B=Q) ---
    f32x4 S0, S1, S2, S3;
#define QKNT(Sn, nt) {                                                                \
      bf16x8 bk0_ = *(const bf16x8*)&Ks[((nt) * 16 + l16) * 64 + ((quad) ^ (l16 & 7)) * 8];     \
      bf16x8 bk1_ = *(const bf16x8*)&Ks[((nt) * 16 + l16) * 64 + ((4 + quad) ^ (l16 & 7)) * 8]; \
      f32x4 sa_ = {};                                                                 \
      sa_ = MFMA16(bk0_, aq0, sa_);                                                   \
      sa_ = MFMA16(bk1_, aq1, sa_);                                                   \
      Sn = sa_; }
    QKNT(S0, 0) QKNT(S1, 1) QKNT(S2, 2) QKNT(S3, 3)
    // S*[r]: q = wave*16+l16, g = gt*64 + nt*16 + quad*4 + r
    // --- masked exp -> packed bf16, b64 writes into Ps (overlays QPs) ---
    {
      u64 m = Ms[wave * 16 + l16][gt];
      u32 mlo = (u32)m, mhi = (u32)(m >> 32);
      int shq = quad * 4;
      u32 tb0 = mlo >> shq, tb1 = mlo >> (shq + 16);
      u32 tb2 = mhi >> shq, tb3 = mhi >> (shq + 16);
      char* PsB = (char*)QPs + (wave * 16 + l16) * 128 + (quad & 1) * 8;
#define PPACK(Sn, tn, nt) {                                                           \
        f32x2 p0_ = {EXP2(Sn[0]), EXP2(Sn[1])};                                       \
        f32x2 p1_ = {EXP2(Sn[2]), EXP2(Sn[3])};                                       \
        u32 w0_ = __builtin_bit_cast(u32, __builtin_convertvector(p0_, bf16x2));      \
        u32 w1_ = __builtin_bit_cast(u32, __builtin_convertvector(p1_, bf16x2));      \
        u32 ma_ = (u32)((int)((tn) << 31) >> 31);                                     \
        u32 mb_ = (u32)((int)((tn) << 30) >> 31);                                     \
        u32 mc_ = (u32)((int)((tn) << 29) >> 31);                                     \
        u32 md_ = (u32)((int)((tn) << 28) >> 31);                                     \
        w0_ &= (ma_ & 0x0000ffffu) | (mb_ & 0xffff0000u);                             \
        w1_ &= (mc_ & 0x0000ffffu) | (md_ & 0xffff0000u);                             \
        u32x2 wp_ = {w0_, w1_};                                                       \
        int ch_ = ((nt) * 2 + (quad >> 1)) ^ (l16 & 7);                               \
        *(u32x2*)(PsB + ch_ * 16) = wp_; }
      PPACK(S0, tb0, 0) PPACK(S1, tb1, 1) PPACK(S2, tb2, 2) PPACK(S3, tb3, 3)
    }
    // --- PV + denominator (P rows are wave-private: no barrier needed) ---
#define PVKC(kc) {                                                                    \
      bf16x8 ap_ = *(const bf16x8*)&QPs[(wave * 16 + l16) * 64 + ((((kc) * 4 + quad) ^ (l16 & 7)) * 8)]; \
      bf16x8 bv0_ = *(const bf16x8*)&Vs[(0 * 16 + l16) * 64 + ((((kc) * 4 + quad) ^ (l16 & 7)) * 8)];    \
      bf16x8 bv1_ = *(const bf16x8*)&Vs[(1 * 16 + l16) * 64 + ((((kc) * 4 + quad) ^ (l16 & 7)) * 8)];    \
      bf16x8 bv2_ = *(const bf16x8*)&Vs[(2 * 16 + l16) * 64 + ((((kc) * 4 + quad) ^ (l16 & 7)) * 8)];    \
      bf16x8 bv3_ = *(const bf16x8*)&Vs[(3 * 16 + l16) * 64 + ((((kc) * 4 + quad) ^ (l16 & 7)) * 8)];    \
      O0 = MFMA16(ap_, bv0_, O0);                                                     \
      O1 = MFMA16(ap_, bv1_, O1);                                                     \
      O2 = MFMA16(ap_, bv2_, O2);                                                     \
      O3 = MFMA16(ap_, bv3_, O3);                                                     \
      Oden = MFMA16(ap_, ones, Oden); }
    PVKC(0) PVKC(1)
    __syncthreads();               // all LDS reads of this gt done
    if (nxt < 32) {
      STOREKV();                   // vmcnt wait lands here: loads flew during compute
      if (ngt == 0) STOREQM();
    }
    __syncthreads();               // stores visible for next gt
  }
#pragma unroll
  for (int r = 0; r < 4; r++) {
    float den = Oden[r];           // every lane holds its rows' denominator
    float i0 = (den > 0.f) ? O0[r] / den : 0.f;
    float i1 = (den > 0.f) ? O1[r] / den : 0.f;
    float i2 = (den > 0.f) ? O2[r] / den : 0.f;
    float i3 = (den > 0.f) ? O3[r] / den : 0.f;
    size_t base = ((size_t)(h * 16 + b) * 512 + q0 + wave * 16 + quad * 4 + r) * 64 + l16;
    heads[base + 0]  = f2bf(i0);
    heads[base + 16] = f2bf(i1);
    heads[base + 32] = f2bf(i2);
    heads[base + 48] = f2bf(i3);
  }
}

// ---------------------------------------------------------------- pass C: out = heads x W_out
// out(8192 x 512) = heads[(b,q),(h,v)=512] * Wot. 64x64 tile, K-loop over h.
// Reg-staged prefetch (round-4/5 proven).
__global__ __launch_bounds__(256) void gemm_out_k(const u16* __restrict__ heads,
                                                  const u16* __restrict__ Wot,
                                                  float* __restrict__ out) {
  __shared__ __align__(16) u16 As[4096];
  __shared__ __align__(16) u16 Bs[4096];
  int t = threadIdx.x;
  int wave = t >> 6, lane = t & 63, quad = lane >> 4, l16 = lane & 15;
  int m0 = blockIdx.x * 64, e0 = blockIdx.y * 64;
  int b = m0 >> 9, q0 = m0 & 511;
  int lr8 = lane >> 3, lc8 = (lane & 7) ^ lr8;
  f32x4 acc[4] = {};
  char* AsB = (char*)As;
  char* BsB = (char*)Bs;
  int stO = wave * 2048 + lane * 16;   // byte offset (j=0); j=1 adds 1024
  // per-thread global bases (h=0, j=0); h strides: heads 524288 u16, Wot 32768 u16
  const u16* hg = heads + ((size_t)(b * 512) + q0 + wave * 16 + lr8) * 64 + lc8 * 8;
  const u16* wg = Wot + ((size_t)(e0 + wave * 16 + lr8)) * 64 + lc8 * 8;

  uint4 gA0, gA1, gB0, gB1;
#define GO_LD(h_) {                                                        \
    gA0 = *(const uint4*)(hg + (size_t)(h_) * 524288);                     \
    gA1 = *(const uint4*)(hg + (size_t)(h_) * 524288 + 512);               \
    gB0 = *(const uint4*)(wg + (size_t)(h_) * 32768);                      \
    gB1 = *(const uint4*)(wg + (size_t)(h_) * 32768 + 512); }
#define GO_ST() {                                                          \
    *(uint4*)(AsB + stO)        = gA0;                                     \
    *(uint4*)(AsB + stO + 1024) = gA1;                                     \
    *(uint4*)(BsB + stO)        = gB0;                                     \
    *(uint4*)(BsB + stO + 1024) = gB1; }

  // prologue: stage h=0
  GO_LD(0);
  GO_ST();
  __syncthreads();

  for (int h = 0; h < 8; h++) {
    if (h < 7) GO_LD(h + 1);           // flies under the compute below
#pragma unroll
    for (int kc = 0; kc < 2; kc++) {
      bf16x8 af = *(const bf16x8*)&As[(wave * 16 + l16) * 64 + ((kc * 4 + quad) ^ (l16 & 7)) * 8];
#pragma unroll
      for (int nt = 0; nt < 4; nt++) {
        bf16x8 bfr = *(const bf16x8*)&Bs[(nt * 16 + l16) * 64 + ((kc * 4 + quad) ^ (l16 & 7)) * 8];
        acc[nt] = MFMA16(af, bfr, acc[nt]);
      }
    }
    if (h < 7) {
      __syncthreads();                 // all LDS reads of step h done
      GO_ST();                         // vmcnt wait here: loads flew during compute
      __syncthreads();                 // stores visible
    }
  }
#pragma unroll
  for (int nt = 0; nt < 4; nt++)
#pragma unroll
    for (int r = 0; r < 4; r++)
      out[((size_t)(b * 512 + q0 + wave * 16 + quad * 4 + r)) * 512 + e0 + nt * 16 + l16] = acc[nt][r];
}

// ---------------------------------------------------------------- launch

extern "C" void kernel_launch(void* const* d_in, const int* in_sizes, int n_in,
                              void* d_out, int out_size, void* d_ws, size_t ws_size,
                              hipStream_t stream) {
  char* ws = (char*)d_ws;
  // workspace layout (total 126,353,408 B)
  u16* qb    = (u16*)(ws + 0);            //   8,388,608
  u16* Wbt   = (u16*)(ws + 8388608);      //   6,291,456
  u16* Wot   = (u16*)(ws + 14680064);     //     524,288
  u64* RB    = (u64*)(ws + 15204352);     //   2,097,152  (bit-packed masks)
  u16* P     = (u16*)(ws + 17301504);     // 100,663,296
  u16* heads = (u16*)(ws + 117964800);    //   8,388,608
  float* out = (float*)d_out;

  PrepArgs pa;
  pa.q   = (const float*)d_in[0];
  pa.att = (const int*)d_in[1];
  pa.grp = (const int*)d_in[2];
  pa.sd  = (const int*)d_in[3];
  for (int j = 0; j < 12; j++) pa.w[j] = (const float*)d_in[4 + j];
  pa.wout = (const float*)d_in[16];
  pa.qb = qb; pa.Wbt = Wbt; pa.Wot = Wot; pa.RB = RB;

  prep_main_k<<<3008, 256, 0, stream>>>(pa);
  pack_cols_t_k<<<256, 256, 0, stream>>>(RB);
  gemm_proj_k<<<dim3(64, 48), 256, 0, stream>>>(qb, Wbt, P);
  attn_k<<<1024, 256, 0, stream>>>(P, RB, heads);
  gemm_out_k<<<dim3(128, 8), 256, 0, stream>>>(heads, Wot, out);
}

// Round 13
// 298.928 us; speedup vs baseline: 1.0640x; 1.0640x over previous
//
#include <hip/hip_runtime.h>

// Problem constants: H=8, B=16, G=512, NQ=512, D=512, KD=VD=64, E=512, NORM=0.125
using u8 = unsigned char;
using u16 = unsigned short;
using u32 = unsigned int;
using u64 = unsigned long long;

typedef __attribute__((ext_vector_type(8))) __bf16 bf16x8;
typedef __attribute__((ext_vector_type(2))) __bf16 bf16x2;
typedef __attribute__((ext_vector_type(8))) u16 u16x8;
typedef __attribute__((ext_vector_type(4))) float f32x4;
typedef __attribute__((ext_vector_type(2))) float f32x2;
typedef __attribute__((ext_vector_type(2))) u32 u32x2;

#define MFMA16(A, B, C) __builtin_amdgcn_mfma_f32_16x16x32_bf16((A), (B), (C), 0, 0, 0)

#if __has_builtin(__builtin_amdgcn_exp2f)
#define EXP2(x) __builtin_amdgcn_exp2f(x)
#else
#define EXP2(x) __expf((x)*0.69314718055994531f)
#endif

__device__ __forceinline__ u16 f2bf(float f) {
  u32 u = __builtin_bit_cast(u32, f);
  u += 0x7fffu + ((u >> 16) & 1u);   // round-to-nearest-even
  return (u16)(u >> 16);
}

// async 16B/lane global->LDS DMA. lds dest must be wave-uniform base; lane i
// lands at base + i*16.
__device__ __forceinline__ void gl_lds16(const void* g, void* l) {
  __builtin_amdgcn_global_load_lds(
      (const __attribute__((address_space(1))) void*)g,
      (__attribute__((address_space(3))) void*)l, 16, 0, 0);
}

// ---------------------------------------------------------------- prep
//   prep_main_k: [0,512) pack_rows | [512,896) prep_w | [896,960) prep_wout
//                | [960,3008) prep_q
// (round-10 structure: wide prep_w, bit-transpose pack_cols)

struct PrepArgs {
  const float* q; const int* att; const int* grp; const int* sd;
  const float* w[12]; const float* wout;
  u16* qb; u16* Wbt; u16* Wot; u64* RB;
};

__global__ __launch_bounds__(256) void prep_main_k(PrepArgs a) {
  int bid = blockIdx.x;
  int t = threadIdx.x;
  if (bid < 512) {
    // ---- pack_rows: RB c0/c2/c3 bits (coalesced over g) ----
    int wave = t >> 6, lane = t & 63;
    int b = bid >> 5, qc = bid & 31;
    int q0 = qc * 16 + wave * 4;
#pragma unroll
    for (int r = 0; r < 4; r++) {
      int q = q0 + r;
      size_t rbase = ((size_t)(b * 512 + q)) * 512;
#pragma unroll
      for (int gc = 0; gc < 8; gc++) {
        u64 m0 = __ballot(a.sd [rbase + gc * 64 + lane] != 0);
        u64 m2 = __ballot(a.att[rbase + gc * 64 + lane] != 0);
        u64 m3 = __ballot(a.grp[rbase + gc * 64 + lane] != 0);
        if (lane == 0) {
          size_t ob = ((size_t)(b * 4) * 512 + q) * 8 + gc;
          a.RB[ob]            = m0;   // c0
          a.RB[ob + 2 * 4096] = m2;   // c2
          a.RB[ob + 3 * 4096] = m3;   // c3
        }
      }
    }
  } else if (bid < 896) {
    // ---- prep_w: Wbt[(iw*512+h*64+kk)][d] = W_iw[h][d][kk] * scale ----
    int nb = bid - 512;
    int iw = nb >> 5;
    int rest = nb & 31;
    int h = rest >> 2;
    int d0 = (rest & 3) * 128;
    int kk = t & 63;
    int db0 = t >> 6;
    float scale = ((iw % 3) == 0) ? 0.18033688011112042f : 1.0f;  // 0.125*log2e
    const float* W = a.w[iw] + ((size_t)(h * 512)) * 64 + kk;
    u16* dst = a.Wbt + ((size_t)(iw * 512 + h * 64 + kk)) * 512;
#pragma unroll
    for (int it = 0; it < 4; it++) {
      int d = d0 + (db0 + it * 4) * 8;
      float v0 = W[(size_t)(d + 0) * 64] * scale;
      float v1 = W[(size_t)(d + 1) * 64] * scale;
      float v2 = W[(size_t)(d + 2) * 64] * scale;
      float v3 = W[(size_t)(d + 3) * 64] * scale;
      float v4 = W[(size_t)(d + 4) * 64] * scale;
      float v5 = W[(size_t)(d + 5) * 64] * scale;
      float v6 = W[(size_t)(d + 6) * 64] * scale;
      float v7 = W[(size_t)(d + 7) * 64] * scale;
      u32 w0 = f2bf(v0) | ((u32)f2bf(v1) << 16);
      u32 w1 = f2bf(v2) | ((u32)f2bf(v3) << 16);
      u32 w2 = f2bf(v4) | ((u32)f2bf(v5) << 16);
      u32 w3 = f2bf(v6) | ((u32)f2bf(v7) << 16);
      *(uint4*)(dst + d) = make_uint4(w0, w1, w2, w3);
    }
  } else if (bid < 960) {
    // ---- Wot[h][e][v] = wout[h][v][e]; 64 blocks = (h, e-block of 64) ----
    int nb = bid - 896;
    int h = nb >> 3, e0 = (nb & 7) * 64;
    int ep = t >> 2;        // e' 0..63
    int vc = t & 3;         // v base = vc*16
    const float* src = a.wout + ((size_t)(h * 64)) * 512 + e0 + ep;
#pragma unroll
    for (int j = 0; j < 2; j++) {
      int v0 = vc * 16 + j * 8;
      u32 w0 = f2bf(src[(size_t)(v0 + 0) * 512]) | ((u32)f2bf(src[(size_t)(v0 + 1) * 512]) << 16);
      u32 w1 = f2bf(src[(size_t)(v0 + 2) * 512]) | ((u32)f2bf(src[(size_t)(v0 + 3) * 512]) << 16);
      u32 w2 = f2bf(src[(size_t)(v0 + 4) * 512]) | ((u32)f2bf(src[(size_t)(v0 + 5) * 512]) << 16);
      u32 w3 = f2bf(src[(size_t)(v0 + 6) * 512]) | ((u32)f2bf(src[(size_t)(v0 + 7) * 512]) << 16);
      *(uint4*)&a.Wot[((size_t)(h * 512 + e0 + ep)) * 64 + v0] = make_uint4(w0, w1, w2, w3);
    }
  } else {
    // ---- prep_q: f32 -> bf16, vectorized ----
    int idx = (bid - 960) * 256 + t;
    const float4* p = (const float4*)a.q + (size_t)idx * 2;
    float4 x = p[0], y = p[1];
    u32 w0 = f2bf(x.x) | ((u32)f2bf(x.y) << 16);
    u32 w1 = f2bf(x.z) | ((u32)f2bf(x.w) << 16);
    u32 w2 = f2bf(y.x) | ((u32)f2bf(y.y) << 16);
    u32 w3 = f2bf(y.z) | ((u32)f2bf(y.w) << 16);
    ((uint4*)a.qb)[idx] = make_uint4(w0, w1, w2, w3);
  }
}

// c1 = (q,g)-bit-transpose of c2, per b. One wave per 64x64-bit tile.
__global__ __launch_bounds__(256) void pack_cols_t_k(u64* __restrict__ RB) {
  int t = threadIdx.x;
  int wave = t >> 6, lane = t & 63;
  int tile = blockIdx.x * 4 + wave;           // 0..1023
  int b = tile >> 6, qc = (tile >> 3) & 7, gc = tile & 7;
  u64 R = RB[((size_t)(b * 4 + 2) * 512 + gc * 64 + lane) * 8 + qc];
  u64 out = 0;
#pragma unroll
  for (int j = 0; j < 64; j++) {
    u64 bal = __ballot(((R >> j) & 1) != 0);
    if (lane == j) out = bal;
  }
  RB[((size_t)(b * 4 + 1) * 512 + qc * 64 + lane) * 8 + gc] = out;
}

// ---------------------------------------------------------------- pass A: all 12 projections
// C(8192 x 6144) = qb(8192 x 512) * W(512 x 6144). 128x128 tile, BK=64, 4 waves.
// Round-5 structure (stable best: 75us, MfmaUtil 28): reg-staged prefetch —
// tile k+1's 8 uint4/thread loaded to NAMED registers at top of step k; the
// post-barrier ds_write CONSUMES the regs, pinning the loads early (rounds
// 6/7: MFMA-fed loads get sunk -> exposed L2 latency). B stays in LDS.
// Round-12 lesson: the [128][136] epilogue tile's 34.8KB LDS is NOT worth
// splitting — VGPR bracket (65-128) caps occupancy at 4 blocks/CU anyway,
// and the split epilogue cost 75->103us. Keep this exact form.
__global__ __launch_bounds__(256) void gemm_proj_k(const u16* __restrict__ qb,
                                                   const u16* __restrict__ Wbt,
                                                   u16* __restrict__ P) {
  __shared__ __align__(16) u16 smem[17408];  // As 8192 | Bs 8192; Cs overlays 128x136
  u16* As = smem;
  u16* Bs = smem + 8192;
  int t = threadIdx.x;
  int wave = t >> 6, lane = t & 63, quad = lane >> 4, l16 = lane & 15;
  int m0w = (wave >> 1) * 64, n0w = (wave & 1) * 64;
  int bm = blockIdx.x, bn = blockIdx.y;
  f32x4 acc[4][4] = {};
  int lr8 = lane >> 3;                 // 0..7
  int lc8 = (lane & 7) ^ lr8;         // swizzled logical chunk to fetch
  const u16* ag = qb  + ((size_t)(bm * 128 + wave * 32 + lr8)) * 512 + lc8 * 8;
  const u16* bg = Wbt + ((size_t)(bn * 128 + wave * 32 + lr8)) * 512 + lc8 * 8;
  char* AsB = (char*)As;
  char* BsB = (char*)Bs;
  int stO = wave * 4096 + lane * 16;   // byte offset of this thread's 16B slot (j=0)

  uint4 sA0, sA1, sA2, sA3, sB0, sB1, sB2, sB3;
// named-scalar staging; macros = textual inline, nothing address-taken (rule #20)
#define GLD(k0_) {                                          \
    sA0 = *(const uint4*)(ag + 0 * 4096 + (k0_));           \
    sA1 = *(const uint4*)(ag + 1 * 4096 + (k0_));           \
    sA2 = *(const uint4*)(ag + 2 * 4096 + (k0_));           \
    sA3 = *(const uint4*)(ag + 3 * 4096 + (k0_));           \
    sB0 = *(const uint4*)(bg + 0 * 4096 + (k0_));           \
    sB1 = *(const uint4*)(bg + 1 * 4096 + (k0_));           \
    sB2 = *(const uint4*)(bg + 2 * 4096 + (k0_));           \
    sB3 = *(const uint4*)(bg + 3 * 4096 + (k0_)); }
#define GST() {                                             \
    *(uint4*)(AsB + stO)        = sA0;                      \
    *(uint4*)(AsB + stO + 1024) = sA1;                      \
    *(uint4*)(AsB + stO + 2048) = sA2;                      \
    *(uint4*)(AsB + stO + 3072) = sA3;                      \
    *(uint4*)(BsB + stO)        = sB0;                      \
    *(uint4*)(BsB + stO + 1024) = sB1;                      \
    *(uint4*)(BsB + stO + 2048) = sB2;                      \
    *(uint4*)(BsB + stO + 3072) = sB3; }

  // prologue: stage K-step 0
  GLD(0);
  GST();
  __syncthreads();

  for (int ks = 0; ks < 8; ks++) {
    int k0 = ks * 64;
    if (ks < 7) GLD(k0 + 64);          // flies under the compute below
#pragma unroll
    for (int kc = 0; kc < 2; kc++) {
      bf16x8 am[4], bnf[4];
#pragma unroll
      for (int i = 0; i < 4; i++) {
        int ca = ((kc * 4 + quad) ^ (l16 & 7)) * 8;
        am[i]  = *(const bf16x8*)&As[(m0w + i * 16 + l16) * 64 + ca];
        bnf[i] = *(const bf16x8*)&Bs[(n0w + i * 16 + l16) * 64 + ca];
      }
#pragma unroll
      for (int mt = 0; mt < 4; mt++)
#pragma unroll
        for (int nt = 0; nt < 4; nt++)
          acc[mt][nt] = MFMA16(am[mt], bnf[nt], acc[mt][nt]);
    }
    if (ks < 7) {
      __syncthreads();                 // all LDS reads of step ks done
      GST();                           // own loads ~landed (issued ~770cy ago)
      __syncthreads();                 // stores visible
    }
  }
  // ---------------- epilogue: LDS-staged coalesced stores ----------------
  int iw = bn >> 2;                  // both 64-col groups share iw
  bool isV = (iw % 3) == 2;
  int b  = bm >> 2;
  int n0 = (bm & 3) * 128;
  u16 (*Cs)[136] = (u16(*)[136])smem;  // 128 x 136 u16 = 34816 B
  __syncthreads();
#pragma unroll
  for (int mt = 0; mt < 4; mt++)
#pragma unroll
    for (int nt = 0; nt < 4; nt++)
#pragma unroll
      for (int r = 0; r < 4; r++) {
        int rm = m0w + mt * 16 + quad * 4 + r;
        int cn = n0w + nt * 16 + l16;
        u16 v = f2bf(acc[mt][nt][r]);
        if (!isV) Cs[rm][cn] = v;
        else      Cs[cn][rm] = v;
      }
  __syncthreads();
#pragma unroll
  for (int p = 0; p < 8; p++) {
    int idx = p * 256 + t;
    int seg  = idx & 15;
    int crow = idx >> 4;
    uint4 v = *(const uint4*)&Cs[crow][seg * 8];
    if (!isV) {
      int col = seg * 8;
      int cg = col >> 6, k = col & 63;
      int h = (bn * 2 + cg) & 7;
      u16* dst = P + ((size_t)((iw * 8 + h) * 16 + b)) * 32768 + (size_t)(n0 + crow) * 64 + k;
      *(uint4*)dst = v;
    } else {
      int cg = crow >> 6, k = crow & 63;
      int h = (bn * 2 + cg) & 7;
      u16* dst = P + ((size_t)((iw * 8 + h) * 16 + b)) * 32768 + (size_t)k * 512 + n0 + seg * 8;
      *(uint4*)dst = v;
    }
  }
}

// ---------------------------------------------------------------- pass B: fused masked attention
// 1-D grid, 1024 blocks; block 256 = 4 waves, each wave owns 16 q-rows.
// XCD swizzle keeps each (b,h)'s 512KB K/V panel on one XCD's L2.
// T14 reg-staging with NAMED SCALARS ONLY (rule #20). Swapped QK^T
// (mfma(K,Q)); masked-exp packs via cvt_pk into b64 writes; ones-MFMA
// denominator; raw v_exp_f32 (weights pre-scaled by 0.125*log2e).
__global__ __launch_bounds__(256) void attn_k(const u16* __restrict__ P,
                                              const u64* __restrict__ RB,
                                              u16* __restrict__ heads) {
  __shared__ __align__(16) u16 QPs[4096];    // [64][64]: Q at class start, then P scratch
  __shared__ __align__(16) u16 Ks[4096];     // [64][64] chunk-swizzled
  __shared__ __align__(16) u16 Vs[4096];     // [v][g] chunk-swizzled
  __shared__ __align__(16) u64 Ms[64][10];   // row bitmasks, padded (conflict-free b64)
  int t = threadIdx.x;
  int wave = t >> 6, lane = t & 63, quad = lane >> 4, l16 = lane & 15;
  // id = 8*((bh>>3)*8 + qt) + (bh&7)  — bijective; id%8 keyed to bh
  int id = blockIdx.x;
  int r8 = id & 7, kk2 = id >> 3;
  int bh = ((kk2 >> 3) << 3) | r8;
  int qt = kk2 & 7;
  int b = bh & 15, h = bh >> 4;
  int q0 = qt * 64;
  int lr8 = lane >> 3, lc8 = (lane & 7) ^ lr8;
  f32x4 O0 = {}, O1 = {}, O2 = {}, O3 = {};
  f32x4 Oden = {};
  u16x8 ov = {0x3F80, 0x3F80, 0x3F80, 0x3F80, 0x3F80, 0x3F80, 0x3F80, 0x3F80};
  bf16x8 ones = __builtin_bit_cast(bf16x8, ov);   // bf16 1.0 x8

  uint4 rK0, rK1, rV0, rV1, rQ0, rQ1, rM;
  char* KsB = (char*)Ks;
  char* VsB = (char*)Vs;
  char* QsB = (char*)QPs;
  int stOff = (wave * 16 + lr8) * 128 + (lane & 7) * 16;   // +1024 for second 8 rows

// all staging through named scalars; macros = textual inline, nothing address-taken
#define LOADKV(c, g0) {                                                              \
    const u16* PK_ = P + ((size_t)((3 * (c) + 1) * 8 + h) * 16 + b) * 32768;         \
    const u16* PV_ = P + ((size_t)((3 * (c) + 2) * 8 + h) * 16 + b) * 32768;         \
    rK0 = *(const uint4*)(PK_ + (size_t)((g0) + wave * 16 + lr8) * 64 + lc8 * 8);    \
    rK1 = *(const uint4*)(PK_ + (size_t)((g0) + wave * 16 + 8 + lr8) * 64 + lc8 * 8);\
    rV0 = *(const uint4*)(PV_ + (size_t)(wave * 16 + lr8) * 512 + (g0) + lc8 * 8);   \
    rV1 = *(const uint4*)(PV_ + (size_t)(wave * 16 + 8 + lr8) * 512 + (g0) + lc8 * 8);}
#define STOREKV() {                                                                  \
    *(uint4*)(KsB + stOff)        = rK0;                                             \
    *(uint4*)(KsB + stOff + 1024) = rK1;                                             \
    *(uint4*)(VsB + stOff)        = rV0;                                             \
    *(uint4*)(VsB + stOff + 1024) = rV1; }
#define LOADQM(c) {                                                                  \
    const u16* PQ_ = P + ((size_t)((3 * (c)) * 8 + h) * 16 + b) * 32768;             \
    rQ0 = *(const uint4*)(PQ_ + (size_t)(q0 + wave * 16 + lr8) * 64 + lc8 * 8);      \
    rQ1 = *(const uint4*)(PQ_ + (size_t)(q0 + wave * 16 + 8 + lr8) * 64 + lc8 * 8);  \
    rM  = *(const uint4*)(RB + ((size_t)((b * 4 + (c)) * 512 + q0 + (t >> 2))) * 8 + (t & 3) * 2); }
#define STOREQM() {                                                                  \
    *(uint4*)(QsB + stOff)        = rQ0;                                             \
    *(uint4*)(QsB + stOff + 1024) = rQ1;                                             \
    *(uint4*)((char*)Ms + (t >> 2) * 80 + (t & 3) * 16) = rM; }

  // prologue: tile (c=0, gt=0)
  LOADKV(0, 0);
  LOADQM(0);
  STOREKV();
  STOREQM();
  __syncthreads();

  bf16x8 aq0, aq1;
  for (int tt = 0; tt < 32; tt++) {
    int gt = tt & 7;
    if (gt == 0) {                 // Q fragments gt-invariant: hoist (QPs then free for P)
      aq0 = *(const bf16x8*)&QPs[(wave * 16 + l16) * 64 + ((quad) ^ (l16 & 7)) * 8];
      aq1 = *(const bf16x8*)&QPs[(wave * 16 + l16) * 64 + ((4 + quad) ^ (l16 & 7)) * 8];
    }
    int nxt = tt + 1;
    int nc = nxt >> 3, ngt = nxt & 7;
    if (nxt < 32) {
      LOADKV(nc, ngt * 64);        // issue now; lands during compute below
      if (ngt == 0) LOADQM(nc);
    }
    // --- QK^T, swapped operands: D rows = g (A=K), cols = q (B=Q) ---
    f32x4 S0, S1, S2, S3;
#define QKNT(Sn, nt) {                                                                \
      bf16x8 bk0_ = *(const bf16x8*)&Ks[((nt) * 16 + l16) * 64 + ((quad) ^ (l16 & 7)) * 8];     \
      bf16x8 bk1_ = *(const bf16x8*)&Ks[((nt) * 16 + l16) * 64 + ((4 + quad) ^ (l16 & 7)) * 8]; \
      f32x4 sa_ = {};                                                                 \
      sa_ = MFMA16(bk0_, aq0, sa_);                                                   \
      sa_ = MFMA16(bk1_, aq1, sa_);                                                   \
      Sn = sa_; }
    QKNT(S0, 0) QKNT(S1, 1) QKNT(S2, 2) QKNT(S3, 3)
    // S*[r]: q = wave*16+l16, g = gt*64 + nt*16 + quad*4 + r
    // --- masked exp -> packed bf16, b64 writes into Ps (overlays QPs) ---
    {
      u64 m = Ms[wave * 16 + l16][gt];
      u32 mlo = (u32)m, mhi = (u32)(m >> 32);
      int shq = quad * 4;
      u32 tb0 = mlo >> shq, tb1 = mlo >> (shq + 16);
      u32 tb2 = mhi >> shq, tb3 = mhi >> (shq + 16);
      char* PsB = (char*)QPs + (wave * 16 + l16) * 128 + (quad & 1) * 8;
#define PPACK(Sn, tn, nt) {                                                           \
        f32x2 p0_ = {EXP2(Sn[0]), EXP2(Sn[1])};                                       \
        f32x2 p1_ = {EXP2(Sn[2]), EXP2(Sn[3])};                                       \
        u32 w0_ = __builtin_bit_cast(u32, __builtin_convertvector(p0_, bf16x2));      \
        u32 w1_ = __builtin_bit_cast(u32, __builtin_convertvector(p1_, bf16x2));      \
        u32 ma_ = (u32)((int)((tn) << 31) >> 31);                                     \
        u32 mb_ = (u32)((int)((tn) << 30) >> 31);                                     \
        u32 mc_ = (u32)((int)((tn) << 29) >> 31);                                     \
        u32 md_ = (u32)((int)((tn) << 28) >> 31);                                     \
        w0_ &= (ma_ & 0x0000ffffu) | (mb_ & 0xffff0000u);                             \
        w1_ &= (mc_ & 0x0000ffffu) | (md_ & 0xffff0000u);                             \
        u32x2 wp_ = {w0_, w1_};                                                       \
        int ch_ = ((nt) * 2 + (quad >> 1)) ^ (l16 & 7);                               \
        *(u32x2*)(PsB + ch_ * 16) = wp_; }
      PPACK(S0, tb0, 0) PPACK(S1, tb1, 1) PPACK(S2, tb2, 2) PPACK(S3, tb3, 3)
    }
    // --- PV + denominator (P rows are wave-private: no barrier needed) ---
#define PVKC(kc) {                                                                    \
      bf16x8 ap_ = *(const bf16x8*)&QPs[(wave * 16 + l16) * 64 + ((((kc) * 4 + quad) ^ (l16 & 7)) * 8)]; \
      bf16x8 bv0_ = *(const bf16x8*)&Vs[(0 * 16 + l16) * 64 + ((((kc) * 4 + quad) ^ (l16 & 7)) * 8)];    \
      bf16x8 bv1_ = *(const bf16x8*)&Vs[(1 * 16 + l16) * 64 + ((((kc) * 4 + quad) ^ (l16 & 7)) * 8)];    \
      bf16x8 bv2_ = *(const bf16x8*)&Vs[(2 * 16 + l16) * 64 + ((((kc) * 4 + quad) ^ (l16 & 7)) * 8)];    \
      bf16x8 bv3_ = *(const bf16x8*)&Vs[(3 * 16 + l16) * 64 + ((((kc) * 4 + quad) ^ (l16 & 7)) * 8)];    \
      O0 = MFMA16(ap_, bv0_, O0);                                                     \
      O1 = MFMA16(ap_, bv1_, O1);                                                     \
      O2 = MFMA16(ap_, bv2_, O2);                                                     \
      O3 = MFMA16(ap_, bv3_, O3);                                                     \
      Oden = MFMA16(ap_, ones, Oden); }
    PVKC(0) PVKC(1)
    __syncthreads();               // all LDS reads of this gt done
    if (nxt < 32) {
      STOREKV();                   // vmcnt wait lands here: loads flew during compute
      if (ngt == 0) STOREQM();
    }
    __syncthreads();               // stores visible for next gt
  }
#pragma unroll
  for (int r = 0; r < 4; r++) {
    float den = Oden[r];           // every lane holds its rows' denominator
    float i0 = (den > 0.f) ? O0[r] / den : 0.f;
    float i1 = (den > 0.f) ? O1[r] / den : 0.f;
    float i2 = (den > 0.f) ? O2[r] / den : 0.f;
    float i3 = (den > 0.f) ? O3[r] / den : 0.f;
    size_t base = ((size_t)(h * 16 + b) * 512 + q0 + wave * 16 + quad * 4 + r) * 64 + l16;
    heads[base + 0]  = f2bf(i0);
    heads[base + 16] = f2bf(i1);
    heads[base + 32] = f2bf(i2);
    heads[base + 48] = f2bf(i3);
  }
}

// ---------------------------------------------------------------- pass C: out = heads x W_out
// out(8192 x 512) = heads[(b,q),(h,v)=512] * Wot. 64x64 tile, K-loop over h.
// Reg-staged prefetch (round-4/5 proven).
__global__ __launch_bounds__(256) void gemm_out_k(const u16* __restrict__ heads,
                                                  const u16* __restrict__ Wot,
                                                  float* __restrict__ out) {
  __shared__ __align__(16) u16 As[4096];
  __shared__ __align__(16) u16 Bs[4096];
  int t = threadIdx.x;
  int wave = t >> 6, lane = t & 63, quad = lane >> 4, l16 = lane & 15;
  int m0 = blockIdx.x * 64, e0 = blockIdx.y * 64;
  int b = m0 >> 9, q0 = m0 & 511;
  int lr8 = lane >> 3, lc8 = (lane & 7) ^ lr8;
  f32x4 acc[4] = {};
  char* AsB = (char*)As;
  char* BsB = (char*)Bs;
  int stO = wave * 2048 + lane * 16;   // byte offset (j=0); j=1 adds 1024
  // per-thread global bases (h=0, j=0); h strides: heads 524288 u16, Wot 32768 u16
  const u16* hg = heads + ((size_t)(b * 512) + q0 + wave * 16 + lr8) * 64 + lc8 * 8;
  const u16* wg = Wot + ((size_t)(e0 + wave * 16 + lr8)) * 64 + lc8 * 8;

  uint4 gA0, gA1, gB0, gB1;
#define GO_LD(h_) {                                                        \
    gA0 = *(const uint4*)(hg + (size_t)(h_) * 524288);                     \
    gA1 = *(const uint4*)(hg + (size_t)(h_) * 524288 + 512);               \
    gB0 = *(const uint4*)(wg + (size_t)(h_) * 32768);                      \
    gB1 = *(const uint4*)(wg + (size_t)(h_) * 32768 + 512); }
#define GO_ST() {                                                          \
    *(uint4*)(AsB + stO)        = gA0;                                     \
    *(uint4*)(AsB + stO + 1024) = gA1;                                     \
    *(uint4*)(BsB + stO)        = gB0;                                     \
    *(uint4*)(BsB + stO + 1024) = gB1; }

  // prologue: stage h=0
  GO_LD(0);
  GO_ST();
  __syncthreads();

  for (int h = 0; h < 8; h++) {
    if (h < 7) GO_LD(h + 1);           // flies under the compute below
#pragma unroll
    for (int kc = 0; kc < 2; kc++) {
      bf16x8 af = *(const bf16x8*)&As[(wave * 16 + l16) * 64 + ((kc * 4 + quad) ^ (l16 & 7)) * 8];
#pragma unroll
      for (int nt = 0; nt < 4; nt++) {
        bf16x8 bfr = *(const bf16x8*)&Bs[(nt * 16 + l16) * 64 + ((kc * 4 + quad) ^ (l16 & 7)) * 8];
        acc[nt] = MFMA16(af, bfr, acc[nt]);
      }
    }
    if (h < 7) {
      __syncthreads();                 // all LDS reads of step h done
      GO_ST();                         // vmcnt wait here: loads flew during compute
      __syncthreads();                 // stores visible
    }
  }
#pragma unroll
  for (int nt = 0; nt < 4; nt++)
#pragma unroll
    for (int r = 0; r < 4; r++)
      out[((size_t)(b * 512 + q0 + wave * 16 + quad * 4 + r)) * 512 + e0 + nt * 16 + l16] = acc[nt][r];
}

// ---------------------------------------------------------------- launch

extern "C" void kernel_launch(void* const* d_in, const int* in_sizes, int n_in,
                              void* d_out, int out_size, void* d_ws, size_t ws_size,
                              hipStream_t stream) {
  char* ws = (char*)d_ws;
  // workspace layout (total 126,353,408 B)
  u16* qb    = (u16*)(ws + 0);            //   8,388,608
  u16* Wbt   = (u16*)(ws + 8388608);      //   6,291,456
  u16* Wot   = (u16*)(ws + 14680064);     //     524,288
  u64* RB    = (u64*)(ws + 15204352);     //   2,097,152  (bit-packed masks)
  u16* P     = (u16*)(ws + 17301504);     // 100,663,296
  u16* heads = (u16*)(ws + 117964800);    //   8,388,608
  float* out = (float*)d_out;

  PrepArgs pa;
  pa.q   = (const float*)d_in[0];
  pa.att = (const int*)d_in[1];
  pa.grp = (const int*)d_in[2];
  pa.sd  = (const int*)d_in[3];
  for (int j = 0; j < 12; j++) pa.w[j] = (const float*)d_in[4 + j];
  pa.wout = (const float*)d_in[16];
  pa.qb = qb; pa.Wbt = Wbt; pa.Wot = Wot; pa.RB = RB;

  prep_main_k<<<3008, 256, 0, stream>>>(pa);
  pack_cols_t_k<<<256, 256, 0, stream>>>(RB);
  gemm_proj_k<<<dim3(64, 48), 256, 0, stream>>>(qb, Wbt, P);
  attn_k<<<1024, 256, 0, stream>>>(P, RB, heads);
  gemm_out_k<<<dim3(128, 8), 256, 0, stream>>>(heads, Wot, out);
}

// Round 15
// 282.769 us; speedup vs baseline: 1.1248x; 1.0571x over previous
//
#include <hip/hip_runtime.h>

// Problem constants: H=8, B=16, G=512, NQ=512, D=512, KD=VD=64, E=512, NORM=0.125
using u8 = unsigned char;
using u16 = unsigned short;
using u32 = unsigned int;
using u64 = unsigned long long;

typedef __attribute__((ext_vector_type(8))) __bf16 bf16x8;
typedef __attribute__((ext_vector_type(2))) __bf16 bf16x2;
typedef __attribute__((ext_vector_type(8))) u16 u16x8;
typedef __attribute__((ext_vector_type(4))) float f32x4;
typedef __attribute__((ext_vector_type(2))) float f32x2;
typedef __attribute__((ext_vector_type(2))) u32 u32x2;

#define MFMA16(A, B, C) __builtin_amdgcn_mfma_f32_16x16x32_bf16((A), (B), (C), 0, 0, 0)

#if __has_builtin(__builtin_amdgcn_exp2f)
#define EXP2(x) __builtin_amdgcn_exp2f(x)
#else
#define EXP2(x) __expf((x)*0.69314718055994531f)
#endif

__device__ __forceinline__ u16 f2bf(float f) {
  u32 u = __builtin_bit_cast(u32, f);
  u += 0x7fffu + ((u >> 16) & 1u);   // round-to-nearest-even
  return (u16)(u >> 16);
}

// async 16B/lane global->LDS DMA. lds dest must be wave-uniform base; lane i
// lands at base + i*16.
__device__ __forceinline__ void gl_lds16(const void* g, void* l) {
  __builtin_amdgcn_global_load_lds(
      (const __attribute__((address_space(1))) void*)g,
      (__attribute__((address_space(3))) void*)l, 16, 0, 0);
}

// wave64 nibble->u64 gather: lane l holds 4 mask bits for g=4l..4l+3 in nib[3:0].
// Butterfly combine (xor 1,2,4,8): afterwards every lane in each 16-lane group
// holds the u64 whose bit k = lane (group*16 + k/4)'s nibble bit (k&3), i.e.
// bit k = mask(g = 64*group + k). Branchless selects; shfl default width 64.
__device__ __forceinline__ u64 nib_gather(u32 nib, int lane) {
  u32 a1 = __shfl_xor(nib, 1);
  u32 b  = (lane & 1) ? (a1 | (nib << 4)) : (nib | (a1 << 4));
  u32 a2 = __shfl_xor(b, 2);
  u32 c  = (lane & 2) ? (a2 | (b << 8)) : (b | (a2 << 8));
  u32 a4 = __shfl_xor(c, 4);
  u32 d  = (lane & 4) ? (a4 | (c << 16)) : (c | (a4 << 16));
  u32 a8 = __shfl_xor(d, 8);
  return (lane & 8) ? ((u64)a8 | ((u64)d << 32)) : ((u64)d | ((u64)a8 << 32));
}

// ---------------------------------------------------------------- prep
//   prep_main_k: [0,512) pack_rows | [512,896) prep_w | [896,960) prep_wout
//                | [960,3008) prep_q
// Round-14: pack_rows loads int4 (16B/lane coalesced, G13) + shuffle-tree
// word assembly, replacing scalar-int + ballot (4B/lane was 1/4 of the
// coalescing sweet spot across 50MB of mask reads).

struct PrepArgs {
  const float* q; const int* att; const int* grp; const int* sd;
  const float* w[12]; const float* wout;
  u16* qb; u16* Wbt; u16* Wot; u64* RB;
};

__global__ __launch_bounds__(256) void prep_main_k(PrepArgs a) {
  int bid = blockIdx.x;
  int t = threadIdx.x;
  if (bid < 512) {
    // ---- pack_rows: RB c0/c2/c3 bits; int4 loads + nib_gather ----
    int wave = t >> 6, lane = t & 63;
    int b = bid >> 5, qc = bid & 31;
    int q0 = qc * 16 + wave * 4;
    int gsel = lane >> 4;                       // chunk within half
#pragma unroll
    for (int r = 0; r < 4; r++) {
      int q = q0 + r;
      size_t rbase = ((size_t)(b * 512 + q)) * 512;
#pragma unroll
      for (int gh = 0; gh < 2; gh++) {
        size_t off = rbase + gh * 256 + lane * 4;
        int4 vs = *(const int4*)(a.sd  + off);
        int4 va = *(const int4*)(a.att + off);
        int4 vg = *(const int4*)(a.grp + off);
        u32 n0 = (vs.x ? 1u : 0u) | (vs.y ? 2u : 0u) | (vs.z ? 4u : 0u) | (vs.w ? 8u : 0u);
        u32 n2 = (va.x ? 1u : 0u) | (va.y ? 2u : 0u) | (va.z ? 4u : 0u) | (va.w ? 8u : 0u);
        u32 n3 = (vg.x ? 1u : 0u) | (vg.y ? 2u : 0u) | (vg.z ? 4u : 0u) | (vg.w ? 8u : 0u);
        u64 w0 = nib_gather(n0, lane);
        u64 w2 = nib_gather(n2, lane);
        u64 w3 = nib_gather(n3, lane);
        if ((lane & 15) == 0) {
          int gc = gh * 4 + gsel;
          size_t ob = ((size_t)(b * 4) * 512 + q) * 8 + gc;
          a.RB[ob]            = w0;   // c0
          a.RB[ob + 2 * 4096] = w2;   // c2
          a.RB[ob + 3 * 4096] = w3;   // c3
        }
      }
    }
  } else if (bid < 896) {
    // ---- prep_w: Wbt[(iw*512+h*64+kk)][d] = W_iw[h][d][kk] * scale ----
    int nb = bid - 512;
    int iw = nb >> 5;
    int rest = nb & 31;
    int h = rest >> 2;
    int d0 = (rest & 3) * 128;
    int kk = t & 63;
    int db0 = t >> 6;
    float scale = ((iw % 3) == 0) ? 0.18033688011112042f : 1.0f;  // 0.125*log2e
    const float* W = a.w[iw] + ((size_t)(h * 512)) * 64 + kk;
    u16* dst = a.Wbt + ((size_t)(iw * 512 + h * 64 + kk)) * 512;
#pragma unroll
    for (int it = 0; it < 4; it++) {
      int d = d0 + (db0 + it * 4) * 8;
      float v0 = W[(size_t)(d + 0) * 64] * scale;
      float v1 = W[(size_t)(d + 1) * 64] * scale;
      float v2 = W[(size_t)(d + 2) * 64] * scale;
      float v3 = W[(size_t)(d + 3) * 64] * scale;
      float v4 = W[(size_t)(d + 4) * 64] * scale;
      float v5 = W[(size_t)(d + 5) * 64] * scale;
      float v6 = W[(size_t)(d + 6) * 64] * scale;
      float v7 = W[(size_t)(d + 7) * 64] * scale;
      u32 w0 = f2bf(v0) | ((u32)f2bf(v1) << 16);
      u32 w1 = f2bf(v2) | ((u32)f2bf(v3) << 16);
      u32 w2 = f2bf(v4) | ((u32)f2bf(v5) << 16);
      u32 w3 = f2bf(v6) | ((u32)f2bf(v7) << 16);
      *(uint4*)(dst + d) = make_uint4(w0, w1, w2, w3);
    }
  } else if (bid < 960) {
    // ---- Wot[h][e][v] = wout[h][v][e]; 64 blocks = (h, e-block of 64) ----
    int nb = bid - 896;
    int h = nb >> 3, e0 = (nb & 7) * 64;
    int ep = t >> 2;        // e' 0..63
    int vc = t & 3;         // v base = vc*16
    const float* src = a.wout + ((size_t)(h * 64)) * 512 + e0 + ep;
#pragma unroll
    for (int j = 0; j < 2; j++) {
      int v0 = vc * 16 + j * 8;
      u32 w0 = f2bf(src[(size_t)(v0 + 0) * 512]) | ((u32)f2bf(src[(size_t)(v0 + 1) * 512]) << 16);
      u32 w1 = f2bf(src[(size_t)(v0 + 2) * 512]) | ((u32)f2bf(src[(size_t)(v0 + 3) * 512]) << 16);
      u32 w2 = f2bf(src[(size_t)(v0 + 4) * 512]) | ((u32)f2bf(src[(size_t)(v0 + 5) * 512]) << 16);
      u32 w3 = f2bf(src[(size_t)(v0 + 6) * 512]) | ((u32)f2bf(src[(size_t)(v0 + 7) * 512]) << 16);
      *(uint4*)&a.Wot[((size_t)(h * 512 + e0 + ep)) * 64 + v0] = make_uint4(w0, w1, w2, w3);
    }
  } else {
    // ---- prep_q: f32 -> bf16, vectorized ----
    int idx = (bid - 960) * 256 + t;
    const float4* p = (const float4*)a.q + (size_t)idx * 2;
    float4 x = p[0], y = p[1];
    u32 w0 = f2bf(x.x) | ((u32)f2bf(x.y) << 16);
    u32 w1 = f2bf(x.z) | ((u32)f2bf(x.w) << 16);
    u32 w2 = f2bf(y.x) | ((u32)f2bf(y.y) << 16);
    u32 w3 = f2bf(y.z) | ((u32)f2bf(y.w) << 16);
    ((uint4*)a.qb)[idx] = make_uint4(w0, w1, w2, w3);
  }
}

// c1 = (q,g)-bit-transpose of c2, per b. One wave per 64x64-bit tile.
__global__ __launch_bounds__(256) void pack_cols_t_k(u64* __restrict__ RB) {
  int t = threadIdx.x;
  int wave = t >> 6, lane = t & 63;
  int tile = blockIdx.x * 4 + wave;           // 0..1023
  int b = tile >> 6, qc = (tile >> 3) & 7, gc = tile & 7;
  u64 R = RB[((size_t)(b * 4 + 2) * 512 + gc * 64 + lane) * 8 + qc];
  u64 out = 0;
#pragma unroll
  for (int j = 0; j < 64; j++) {
    u64 bal = __ballot(((R >> j) & 1) != 0);
    if (lane == j) out = bal;
  }
  RB[((size_t)(b * 4 + 1) * 512 + qc * 64 + lane) * 8 + gc] = out;
}

// ---------------------------------------------------------------- pass A: all 12 projections
// C(8192 x 6144) = qb(8192 x 512) * W(512 x 6144). 128x128 tile, BK=64, 4 waves.
// Round-5 structure (stable best: 75us, MfmaUtil 28): reg-staged prefetch —
// tile k+1's 8 uint4/thread loaded to NAMED registers at top of step k; the
// post-barrier ds_write CONSUMES the regs, pinning the loads early (rounds
// 6/7: MFMA-fed loads get sunk -> exposed L2 latency). B stays in LDS.
// Round-12 lesson: the [128][136] epilogue tile's 34.8KB LDS is NOT worth
// splitting — VGPR bracket (65-128) caps occupancy at 4 blocks/CU anyway,
// and the split epilogue cost 75->103us. Keep this exact form.
__global__ __launch_bounds__(256) void gemm_proj_k(const u16* __restrict__ qb,
                                                   const u16* __restrict__ Wbt,
                                                   u16* __restrict__ P) {
  __shared__ __align__(16) u16 smem[17408];  // As 8192 | Bs 8192; Cs overlays 128x136
  u16* As = smem;
  u16* Bs = smem + 8192;
  int t = threadIdx.x;
  int wave = t >> 6, lane = t & 63, quad = lane >> 4, l16 = lane & 15;
  int m0w = (wave >> 1) * 64, n0w = (wave & 1) * 64;
  int bm = blockIdx.x, bn = blockIdx.y;
  f32x4 acc[4][4] = {};
  int lr8 = lane >> 3;                 // 0..7
  int lc8 = (lane & 7) ^ lr8;         // swizzled logical chunk to fetch
  const u16* ag = qb  + ((size_t)(bm * 128 + wave * 32 + lr8)) * 512 + lc8 * 8;
  const u16* bg = Wbt + ((size_t)(bn * 128 + wave * 32 + lr8)) * 512 + lc8 * 8;
  char* AsB = (char*)As;
  char* BsB = (char*)Bs;
  int stO = wave * 4096 + lane * 16;   // byte offset of this thread's 16B slot (j=0)

  uint4 sA0, sA1, sA2, sA3, sB0, sB1, sB2, sB3;
// named-scalar staging; macros = textual inline, nothing address-taken (rule #20)
#define GLD(k0_) {                                          \
    sA0 = *(const uint4*)(ag + 0 * 4096 + (k0_));           \
    sA1 = *(const uint4*)(ag + 1 * 4096 + (k0_));           \
    sA2 = *(const uint4*)(ag + 2 * 4096 + (k0_));           \
    sA3 = *(const uint4*)(ag + 3 * 4096 + (k0_));           \
    sB0 = *(const uint4*)(bg + 0 * 4096 + (k0_));           \
    sB1 = *(const uint4*)(bg + 1 * 4096 + (k0_));           \
    sB2 = *(const uint4*)(bg + 2 * 4096 + (k0_));           \
    sB3 = *(const uint4*)(bg + 3 * 4096 + (k0_)); }
#define GST() {                                             \
    *(uint4*)(AsB + stO)        = sA0;                      \
    *(uint4*)(AsB + stO + 1024) = sA1;                      \
    *(uint4*)(AsB + stO + 2048) = sA2;                      \
    *(uint4*)(AsB + stO + 3072) = sA3;                      \
    *(uint4*)(BsB + stO)        = sB0;                      \
    *(uint4*)(BsB + stO + 1024) = sB1;                      \
    *(uint4*)(BsB + stO + 2048) = sB2;                      \
    *(uint4*)(BsB + stO + 3072) = sB3; }

  // prologue: stage K-step 0
  GLD(0);
  GST();
  __syncthreads();

  for (int ks = 0; ks < 8; ks++) {
    int k0 = ks * 64;
    if (ks < 7) GLD(k0 + 64);          // flies under the compute below
#pragma unroll
    for (int kc = 0; kc < 2; kc++) {
      bf16x8 am[4], bnf[4];
#pragma unroll
      for (int i = 0; i < 4; i++) {
        int ca = ((kc * 4 + quad) ^ (l16 & 7)) * 8;
        am[i]  = *(const bf16x8*)&As[(m0w + i * 16 + l16) * 64 + ca];
        bnf[i] = *(const bf16x8*)&Bs[(n0w + i * 16 + l16) * 64 + ca];
      }
#pragma unroll
      for (int mt = 0; mt < 4; mt++)
#pragma unroll
        for (int nt = 0; nt < 4; nt++)
          acc[mt][nt] = MFMA16(am[mt], bnf[nt], acc[mt][nt]);
    }
    if (ks < 7) {
      __syncthreads();                 // all LDS reads of step ks done
      GST();                           // own loads ~landed (issued ~770cy ago)
      __syncthreads();                 // stores visible
    }
  }
  // ---------------- epilogue: LDS-staged coalesced stores ----------------
  int iw = bn >> 2;                  // both 64-col groups share iw
  bool isV = (iw % 3) == 2;
  int b  = bm >> 2;
  int n0 = (bm & 3) * 128;
  u16 (*Cs)[136] = (u16(*)[136])smem;  // 128 x 136 u16 = 34816 B
  __syncthreads();
#pragma unroll
  for (int mt = 0; mt < 4; mt++)
#pragma unroll
    for (int nt = 0; nt < 4; nt++)
#pragma unroll
      for (int r = 0; r < 4; r++) {
        int rm = m0w + mt * 16 + quad * 4 + r;
        int cn = n0w + nt * 16 + l16;
        u16 v = f2bf(acc[mt][nt][r]);
        if (!isV) Cs[rm][cn] = v;
        else      Cs[cn][rm] = v;
      }
  __syncthreads();
#pragma unroll
  for (int p = 0; p < 8; p++) {
    int idx = p * 256 + t;
    int seg  = idx & 15;
    int crow = idx >> 4;
    uint4 v = *(const uint4*)&Cs[crow][seg * 8];
    if (!isV) {
      int col = seg * 8;
      int cg = col >> 6, k = col & 63;
      int h = (bn * 2 + cg) & 7;
      u16* dst = P + ((size_t)((iw * 8 + h) * 16 + b)) * 32768 + (size_t)(n0 + crow) * 64 + k;
      *(uint4*)dst = v;
    } else {
      int cg = crow >> 6, k = crow & 63;
      int h = (bn * 2 + cg) & 7;
      u16* dst = P + ((size_t)((iw * 8 + h) * 16 + b)) * 32768 + (size_t)k * 512 + n0 + seg * 8;
      *(uint4*)dst = v;
    }
  }
}

// ---------------------------------------------------------------- pass B: fused masked attention
// 1-D grid, 1024 blocks; block 256 = 4 waves, each wave owns 16 q-rows.
// XCD swizzle keeps each (b,h)'s 512KB K/V panel on one XCD's L2.
// T14 reg-staging with NAMED SCALARS ONLY (rule #20). Swapped QK^T
// (mfma(K,Q)); masked-exp packs via cvt_pk into b64 writes; ones-MFMA
// denominator; raw v_exp_f32 (weights pre-scaled by 0.125*log2e).
__global__ __launch_bounds__(256) void attn_k(const u16* __restrict__ P,
                                              const u64* __restrict__ RB,
                                              u16* __restrict__ heads) {
  __shared__ __align__(16) u16 QPs[4096];    // [64][64]: Q at class start, then P scratch
  __shared__ __align__(16) u16 Ks[4096];     // [64][64] chunk-swizzled
  __shared__ __align__(16) u16 Vs[4096];     // [v][g] chunk-swizzled
  __shared__ __align__(16) u64 Ms[64][10];   // row bitmasks, padded (conflict-free b64)
  int t = threadIdx.x;
  int wave = t >> 6, lane = t & 63, quad = lane >> 4, l16 = lane & 15;
  // id = 8*((bh>>3)*8 + qt) + (bh&7)  — bijective; id%8 keyed to bh
  int id = blockIdx.x;
  int r8 = id & 7, kk2 = id >> 3;
  int bh = ((kk2 >> 3) << 3) | r8;
  int qt = kk2 & 7;
  int b = bh & 15, h = bh >> 4;
  int q0 = qt * 64;
  int lr8 = lane >> 3, lc8 = (lane & 7) ^ lr8;
  f32x4 O0 = {}, O1 = {}, O2 = {}, O3 = {};
  f32x4 Oden = {};
  u16x8 ov = {0x3F80, 0x3F80, 0x3F80, 0x3F80, 0x3F80, 0x3F80, 0x3F80, 0x3F80};
  bf16x8 ones = __builtin_bit_cast(bf16x8, ov);   // bf16 1.0 x8

  uint4 rK0, rK1, rV0, rV1, rQ0, rQ1, rM;
  char* KsB = (char*)Ks;
  char* VsB = (char*)Vs;
  char* QsB = (char*)QPs;
  int stOff = (wave * 16 + lr8) * 128 + (lane & 7) * 16;   // +1024 for second 8 rows

// all staging through named scalars; macros = textual inline, nothing address-taken
#define LOADKV(c, g0) {                                                              \
    const u16* PK_ = P + ((size_t)((3 * (c) + 1) * 8 + h) * 16 + b) * 32768;         \
    const u16* PV_ = P + ((size_t)((3 * (c) + 2) * 8 + h) * 16 + b) * 32768;         \
    rK0 = *(const uint4*)(PK_ + (size_t)((g0) + wave * 16 + lr8) * 64 + lc8 * 8);    \
    rK1 = *(const uint4*)(PK_ + (size_t)((g0) + wave * 16 + 8 + lr8) * 64 + lc8 * 8);\
    rV0 = *(const uint4*)(PV_ + (size_t)(wave * 16 + lr8) * 512 + (g0) + lc8 * 8);   \
    rV1 = *(const uint4*)(PV_ + (size_t)(wave * 16 + 8 + lr8) * 512 + (g0) + lc8 * 8);}
#define STOREKV() {                                                                  \
    *(uint4*)(KsB + stOff)        = rK0;                                             \
    *(uint4*)(KsB + stOff + 1024) = rK1;                                             \
    *(uint4*)(VsB + stOff)        = rV0;                                             \
    *(uint4*)(VsB + stOff + 1024) = rV1; }
#define LOADQM(c) {                                                                  \
    const u16* PQ_ = P + ((size_t)((3 * (c)) * 8 + h) * 16 + b) * 32768;             \
    rQ0 = *(const uint4*)(PQ_ + (size_t)(q0 + wave * 16 + lr8) * 64 + lc8 * 8);      \
    rQ1 = *(const uint4*)(PQ_ + (size_t)(q0 + wave * 16 + 8 + lr8) * 64 + lc8 * 8);  \
    rM  = *(const uint4*)(RB + ((size_t)((b * 4 + (c)) * 512 + q0 + (t >> 2))) * 8 + (t & 3) * 2); }
#define STOREQM() {                                                                  \
    *(uint4*)(QsB + stOff)        = rQ0;                                             \
    *(uint4*)(QsB + stOff + 1024) = rQ1;                                             \
    *(uint4*)((char*)Ms + (t >> 2) * 80 + (t & 3) * 16) = rM; }

  // prologue: tile (c=0, gt=0)
  LOADKV(0, 0);
  LOADQM(0);
  STOREKV();
  STOREQM();
  __syncthreads();

  bf16x8 aq0, aq1;
  for (int tt = 0; tt < 32; tt++) {
    int gt = tt & 7;
    if (gt == 0) {                 // Q fragments gt-invariant: hoist (QPs then free for P)
      aq0 = *(const bf16x8*)&QPs[(wave * 16 + l16) * 64 + ((quad) ^ (l16 & 7)) * 8];
      aq1 = *(const bf16x8*)&QPs[(wave * 16 + l16) * 64 + ((4 + quad) ^ (l16 & 7)) * 8];
    }
    int nxt = tt + 1;
    int nc = nxt >> 3, ngt = nxt & 7;
    if (nxt < 32) {
      LOADKV(nc, ngt * 64);        // issue now; lands during compute below
      if (ngt == 0) LOADQM(nc);
    }
    // --- QK^T, swapped operands: D rows = g (A=K), cols = q (B=Q) ---
    f32x4 S0, S1, S2, S3;
#define QKNT(Sn, nt) {                                                                \
      bf16x8 bk0_ = *(const bf16x8*)&Ks[((nt) * 16 + l16) * 64 + ((quad) ^ (l16 & 7)) * 8];     \
      bf16x8 bk1_ = *(const bf16x8*)&Ks[((nt) * 16 + l16) * 64 + ((4 + quad) ^ (l16 & 7)) * 8]; \
      f32x4 sa_ = {};                                                                 \
      sa_ = MFMA16(bk0_, aq0, sa_);                                                   \
      sa_ = MFMA16(bk1_, aq1, sa_);                                                   \
      Sn = sa_; }
    QKNT(S0, 0) QKNT(S1, 1) QKNT(S2, 2) QKNT(S3, 3)
    // S*[r]: q = wave*16+l16, g = gt*64 + nt*16 + quad*4 + r
    // --- masked exp -> packed bf16, b64 writes into Ps (overlays QPs) ---
    {
      u64 m = Ms[wave * 16 + l16][gt];
      u32 mlo = (u32)m, mhi = (u32)(m >> 32);
      int shq = quad * 4;
      u32 tb0 = mlo >> shq, tb1 = mlo >> (shq + 16);
      u32 tb2 = mhi >> shq, tb3 = mhi >> (shq + 16);
      char* PsB = (char*)QPs + (wave * 16 + l16) * 128 + (quad & 1) * 8;
#define PPACK(Sn, tn, nt) {                                                           \
        f32x2 p0_ = {EXP2(Sn[0]), EXP2(Sn[1])};                                       \
        f32x2 p1_ = {EXP2(Sn[2]), EXP2(Sn[3])};                                       \
        u32 w0_ = __builtin_bit_cast(u32, __builtin_convertvector(p0_, bf16x2));      \
        u32 w1_ = __builtin_bit_cast(u32, __builtin_convertvector(p1_, bf16x2));      \
        u32 ma_ = (u32)((int)((tn) << 31) >> 31);                                     \
        u32 mb_ = (u32)((int)((tn) << 30) >> 31);                                     \
        u32 mc_ = (u32)((int)((tn) << 29) >> 31);                                     \
        u32 md_ = (u32)((int)((tn) << 28) >> 31);                                     \
        w0_ &= (ma_ & 0x0000ffffu) | (mb_ & 0xffff0000u);                             \
        w1_ &= (mc_ & 0x0000ffffu) | (md_ & 0xffff0000u);                             \
        u32x2 wp_ = {w0_, w1_};                                                       \
        int ch_ = ((nt) * 2 + (quad >> 1)) ^ (l16 & 7);                               \
        *(u32x2*)(PsB + ch_ * 16) = wp_; }
      PPACK(S0, tb0, 0) PPACK(S1, tb1, 1) PPACK(S2, tb2, 2) PPACK(S3, tb3, 3)
    }
    // --- PV + denominator (P rows are wave-private: no barrier needed) ---
#define PVKC(kc) {                                                                    \
      bf16x8 ap_ = *(const bf16x8*)&QPs[(wave * 16 + l16) * 64 + ((((kc) * 4 + quad) ^ (l16 & 7)) * 8)]; \
      bf16x8 bv0_ = *(const bf16x8*)&Vs[(0 * 16 + l16) * 64 + ((((kc) * 4 + quad) ^ (l16 & 7)) * 8)];    \
      bf16x8 bv1_ = *(const bf16x8*)&Vs[(1 * 16 + l16) * 64 + ((((kc) * 4 + quad) ^ (l16 & 7)) * 8)];    \
      bf16x8 bv2_ = *(const bf16x8*)&Vs[(2 * 16 + l16) * 64 + ((((kc) * 4 + quad) ^ (l16 & 7)) * 8)];    \
      bf16x8 bv3_ = *(const bf16x8*)&Vs[(3 * 16 + l16) * 64 + ((((kc) * 4 + quad) ^ (l16 & 7)) * 8)];    \
      O0 = MFMA16(ap_, bv0_, O0);                                                     \
      O1 = MFMA16(ap_, bv1_, O1);                                                     \
      O2 = MFMA16(ap_, bv2_, O2);                                                     \
      O3 = MFMA16(ap_, bv3_, O3);                                                     \
      Oden = MFMA16(ap_, ones, Oden); }
    PVKC(0) PVKC(1)
    __syncthreads();               // all LDS reads of this gt done
    if (nxt < 32) {
      STOREKV();                   // vmcnt wait lands here: loads flew during compute
      if (ngt == 0) STOREQM();
    }
    __syncthreads();               // stores visible for next gt
  }
#pragma unroll
  for (int r = 0; r < 4; r++) {
    float den = Oden[r];           // every lane holds its rows' denominator
    float i0 = (den > 0.f) ? O0[r] / den : 0.f;
    float i1 = (den > 0.f) ? O1[r] / den : 0.f;
    float i2 = (den > 0.f) ? O2[r] / den : 0.f;
    float i3 = (den > 0.f) ? O3[r] / den : 0.f;
    size_t base = ((size_t)(h * 16 + b) * 512 + q0 + wave * 16 + quad * 4 + r) * 64 + l16;
    heads[base + 0]  = f2bf(i0);
    heads[base + 16] = f2bf(i1);
    heads[base + 32] = f2bf(i2);
    heads[base + 48] = f2bf(i3);
  }
}

// ---------------------------------------------------------------- pass C: out = heads x W_out
// out(8192 x 512) = heads[(b,q),(h,v)=512] * Wot. 64x64 tile, K-loop over h.
// Reg-staged prefetch (round-4/5 proven).
__global__ __launch_bounds__(256) void gemm_out_k(const u16* __restrict__ heads,
                                                  const u16* __restrict__ Wot,
                                                  float* __restrict__ out) {
  __shared__ __align__(16) u16 As[4096];
  __shared__ __align__(16) u16 Bs[4096];
  int t = threadIdx.x;
  int wave = t >> 6, lane = t & 63, quad = lane >> 4, l16 = lane & 15;
  int m0 = blockIdx.x * 64, e0 = blockIdx.y * 64;
  int b = m0 >> 9, q0 = m0 & 511;
  int lr8 = lane >> 3, lc8 = (lane & 7) ^ lr8;
  f32x4 acc[4] = {};
  char* AsB = (char*)As;
  char* BsB = (char*)Bs;
  int stO = wave * 2048 + lane * 16;   // byte offset (j=0); j=1 adds 1024
  // per-thread global bases (h=0, j=0); h strides: heads 524288 u16, Wot 32768 u16
  const u16* hg = heads + ((size_t)(b * 512) + q0 + wave * 16 + lr8) * 64 + lc8 * 8;
  const u16* wg = Wot + ((size_t)(e0 + wave * 16 + lr8)) * 64 + lc8 * 8;

  uint4 gA0, gA1, gB0, gB1;
#define GO_LD(h_) {                                                        \
    gA0 = *(const uint4*)(hg + (size_t)(h_) * 524288);                     \
    gA1 = *(const uint4*)(hg + (size_t)(h_) * 524288 + 512);               \
    gB0 = *(const uint4*)(wg + (size_t)(h_) * 32768);                      \
    gB1 = *(const uint4*)(wg + (size_t)(h_) * 32768 + 512); }
#define GO_ST() {                                                          \
    *(uint4*)(AsB + stO)        = gA0;                                     \
    *(uint4*)(AsB + stO + 1024) = gA1;                                     \
    *(uint4*)(BsB + stO)        = gB0;                                     \
    *(uint4*)(BsB + stO + 1024) = gB1; }

  // prologue: stage h=0
  GO_LD(0);
  GO_ST();
  __syncthreads();

  for (int h = 0; h < 8; h++) {
    if (h < 7) GO_LD(h + 1);           // flies under the compute below
#pragma unroll
    for (int kc = 0; kc < 2; kc++) {
      bf16x8 af = *(const bf16x8*)&As[(wave * 16 + l16) * 64 + ((kc * 4 + quad) ^ (l16 & 7)) * 8];
#pragma unroll
      for (int nt = 0; nt < 4; nt++) {
        bf16x8 bfr = *(const bf16x8*)&Bs[(nt * 16 + l16) * 64 + ((kc * 4 + quad) ^ (l16 & 7)) * 8];
        acc[nt] = MFMA16(af, bfr, acc[nt]);
      }
    }
    if (h < 7) {
      __syncthreads();                 // all LDS reads of step h done
      GO_ST();                         // vmcnt wait here: loads flew during compute
      __syncthreads();                 // stores visible
    }
  }
#pragma unroll
  for (int nt = 0; nt < 4; nt++)
#pragma unroll
    for (int r = 0; r < 4; r++)
      out[((size_t)(b * 512 + q0 + wave * 16 + quad * 4 + r)) * 512 + e0 + nt * 16 + l16] = acc[nt][r];
}

// ---------------------------------------------------------------- launch

extern "C" void kernel_launch(void* const* d_in, const int* in_sizes, int n_in,
                              void* d_out, int out_size, void* d_ws, size_t ws_size,
                              hipStream_t stream) {
  char* ws = (char*)d_ws;
  // workspace layout (total 126,353,408 B)
  u16* qb    = (u16*)(ws + 0);            //   8,388,608
  u16* Wbt   = (u16*)(ws + 8388608);      //   6,291,456
  u16* Wot   = (u16*)(ws + 14680064);     //     524,288
  u64* RB    = (u64*)(ws + 15204352);     //   2,097,152  (bit-packed masks)
  u16* P     = (u16*)(ws + 17301504);     // 100,663,296
  u16* heads = (u16*)(ws + 117964800);    //   8,388,608
  float* out = (float*)d_out;

  PrepArgs pa;
  pa.q   = (const float*)d_in[0];
  pa.att = (const int*)d_in[1];
  pa.grp = (const int*)d_in[2];
  pa.sd  = (const int*)d_in[3];
  for (int j = 0; j < 12; j++) pa.w[j] = (const float*)d_in[4 + j];
  pa.wout = (const float*)d_in[16];
  pa.qb = qb; pa.Wbt = Wbt; pa.Wot = Wot; pa.RB = RB;

  prep_main_k<<<3008, 256, 0, stream>>>(pa);
  pack_cols_t_k<<<256, 256, 0, stream>>>(RB);
  gemm_proj_k<<<dim3(64, 48), 256, 0, stream>>>(qb, Wbt, P);
  attn_k<<<1024, 256, 0, stream>>>(P, RB, heads);
  gemm_out_k<<<dim3(128, 8), 256, 0, stream>>>(heads, Wot, out);
}